// Round 7
// baseline (223.367 us; speedup 1.0000x reference)
//
#include <hip/hip_runtime.h>

// Cost-volume / correlation layer, fp32.
// out[b, dy*9+dx, h, w] = (1/C) * sum_c first[b,c,h,w] * second[b,c,h+dy-4,w+dx-4]
// (zero outside bounds).  B=8, C=128, H=W=128, search_range=4 -> 81 offsets.
//
// Round-10: R9 falsified the barrier-bubble theory (32 vs 128 barriers:
// per-channel cost unchanged ~1600cy/CU).  Cost empirically tracks DS
// instruction count (~21.6cy per ds_read_b128, 4 per thread per channel).
// Probe: cut DS reads 4 -> 3 by keeping `first` in registers (it is
// thread-private; LDS was a pure round-trip).  R8's version of this raced
// (hand-counted vmcnt over compiler-invisible asm loads).  This version is
// race-free by construction:
//   - f loaded with plain C++ loads (compiler manages waits; L1 absorbs the
//     9-wave redundancy: 6KB/channel/block working set).
//   - ALL manual waits replaced by __syncthreads() (full vmcnt(0)+lgkmcnt(0)
//     drain + barrier = real memory fence).  stage(k+2) overwrites buf k-2,
//     whose readers drained at the k-1 barrier -> provably safe.  No asm.
//   - DMA still issued 2 iterations ahead (forced complete 1 ahead): >=1
//     channel (~1500cy) of flight vs ~900cy HBM latency.

constexpr int B = 8, C = 128, H = 128, W = 128;
constexpr int RNG = 4, MO = 9;        // search range, max_offset
constexpr int RW  = 4;                // pixels per thread along w
constexpr int TH  = 2;                // h rows per block
constexpr int HWc = H * W;            // 16384
constexpr int SROWS = TH + 2 * RNG;   // 10 second rows per block
constexpr int SLAB  = SROWS * W;      // 1280 floats = 5 KiB per buffer
constexpr int NBUF  = 4;              // buffers (power of 2 -> cheap index)

typedef float f32x4 __attribute__((ext_vector_type(4)));

__global__ __launch_bounds__(576)
__attribute__((amdgpu_waves_per_eu(2, 5)))
void corr_kernel(const float* __restrict__ first,
                 const float* __restrict__ second,
                 float* __restrict__ out)
{
    const int tx = threadIdx.x;           // 0..31
    const int hy = threadIdx.y;           // 0..1
    const int dz = threadIdx.z;           // 0..8  (wave id == dz)
    const int h0 = blockIdx.x * TH;       // 0..126 (even)
    const int b  = blockIdx.y;
    const int w0 = tx * RW;               // 0..124
    const int lane = tx + 32 * hy;        // 0..63

    __shared__ __align__(16) float slab[NBUF][SLAB];   // 20 KiB

    // staging roles: waves dz = 0..4 stage second row-pair q = dz:
    // global rows (h0-4+2q, h0-4+2q+1) -> slab rows 2q, 2q+1.  h0 is even so
    // pairs are even-aligned => each pair is fully-valid or fully-invalid;
    // invalid pairs are clamp-staged (finite data, never read: the reader
    // with srow out of [0,128) has rvalid=false and multiplies acc by 0).
    const bool do_stage = (dz < 5);
    const float* gsrc = nullptr;
    int ldsoff = 0;
    if (do_stage) {
        const int r0 = h0 - RNG + 2 * dz;                 // even, [-4,130]
        const int cs = r0 < 0 ? 0 : (r0 > H - 2 ? H - 2 : r0);
        gsrc  = second + (size_t)b * C * HWc + cs * W + lane * 4;
        ldsoff = 2 * dz * W;
    }

    // compute-side constants
    const int  srow   = h0 + hy + dz - RNG;
    const bool rvalid = (srow >= 0) && (srow < H);
    const bool ledge  = (tx == 0);
    const bool redge  = (tx == 31);
    const int off0  = ledge ? 0       : (w0 - 4);   // 16B-aligned in-row
    const int off2  = redge ? (W - 8) : (w0 + 4);
    const int sbase = (hy + dz) * W;                // slab row hy+dz (0..9)

    float acc[MO][RW];
#pragma unroll
    for (int i = 0; i < MO; ++i)
#pragma unroll
        for (int p = 0; p < RW; ++p) acc[i][p] = 0.0f;

#define STAGE(k)                                                            \
    if (do_stage) {                                                         \
        __builtin_amdgcn_global_load_lds(                                   \
            (const __attribute__((address_space(1))) void*)                 \
                (gsrc + (size_t)(k) * HWc),                                 \
            (__attribute__((address_space(3))) void*)                       \
                (&slab[(k) & (NBUF - 1)][ldsoff]),                          \
            16, 0, 0);                                                      \
    }

    // `first` path: thread-private, registers only (no LDS round-trip).
    const float* fp = first + (size_t)b * C * HWc + (h0 + hy) * W + w0;

    f32x4 fcur = *(const f32x4*)(fp);     // c = 0
    fp += HWc;

    STAGE(0)
    STAGE(1)

    for (int k = 0; k < C; ++k) {
        // Full drain + barrier: stage(k) (and k+1) complete, all waves'
        // ds_reads of iter k-1 retired -> buf (k-2)&3 is dead and may be
        // overwritten by stage(k+2) below.  Also a compiler memory fence:
        // no ds_read can sink past it.
        __syncthreads();

        if (k < C - 2) STAGE(k + 2)

        f32x4 fnxt;
        if (k < C - 1) { fnxt = *(const f32x4*)(fp); fp += HWc; }

        const float* sb = slab[k & (NBUF - 1)];
        f32x4 a0 = *(const f32x4*)(sb + sbase + off0);
        f32x4 a1 = *(const f32x4*)(sb + sbase + w0);
        f32x4 a2 = *(const f32x4*)(sb + sbase + off2);
        if (ledge) a0 = (f32x4){0.f, 0.f, 0.f, 0.f};
        if (redge) a2 = (f32x4){0.f, 0.f, 0.f, 0.f};
        const float s[12] = {a0.x, a0.y, a0.z, a0.w,
                             a1.x, a1.y, a1.z, a1.w,
                             a2.x, a2.y, a2.z, a2.w};
        const float fvv[RW] = {fcur.x, fcur.y, fcur.z, fcur.w};
#pragma unroll
        for (int dx = 0; dx < MO; ++dx)
#pragma unroll
            for (int p = 0; p < RW; ++p)
                acc[dx][p] += fvv[p] * s[p + dx];

        fcur = fnxt;
    }
#undef STAGE

    // invalid srow => result must be 0 (acc holds finite garbage; *0 is safe)
    const float inv = rvalid ? (1.0f / (float)C) : 0.0f;
    float* obase = out + ((size_t)b * (MO * MO) + (size_t)dz * MO) * HWc
                       + (size_t)(h0 + hy) * W + w0;
#pragma unroll
    for (int dx = 0; dx < MO; ++dx) {
        f32x4 v = {acc[dx][0] * inv, acc[dx][1] * inv,
                   acc[dx][2] * inv, acc[dx][3] * inv};
        *(f32x4*)(obase + (size_t)dx * HWc) = v;
    }
}

extern "C" void kernel_launch(void* const* d_in, const int* in_sizes, int n_in,
                              void* d_out, int out_size, void* d_ws, size_t ws_size,
                              hipStream_t stream) {
    const float* first  = (const float*)d_in[0];
    const float* second = (const float*)d_in[1];
    float* out = (float*)d_out;

    dim3 grid(H / TH, B);       // (64, 8) = 512 blocks = 2 per CU
    dim3 block(32, TH, MO);     // 576 threads = 9 waves, wave id == dy
    corr_kernel<<<grid, block, 0, stream>>>(first, second, out);
}